// Round 13
// baseline (175.214 us; speedup 1.0000x reference)
//
#include <hip/hip_runtime.h>
#include <hip/hip_bf16.h>

// Problem constants (B,S,D,H fixed by setup_inputs)
#define B_  8
#define S_  1024
#define D_  768
#define H_  12
#define DH_ 64

typedef __attribute__((ext_vector_type(8))) short bf16x8;
typedef __attribute__((ext_vector_type(4))) float f32x4;
typedef __attribute__((ext_vector_type(16))) float f32x16;

__device__ inline short f2bf(float f) {
    unsigned u = __builtin_bit_cast(unsigned, f);
    u = (u + 0x7fffu + ((u >> 16) & 1u)) >> 16;   // RNE
    return (short)u;
}
__device__ inline float exp2_fast(float x) {
    float r; asm("v_exp_f32 %0, %1" : "=v"(r) : "v"(x)); return r;
}
__device__ inline unsigned cvt_pk_bf16(float lo, float hi) {
    unsigned r; asm("v_cvt_pk_bf16_f32 %0, %1, %2" : "=v"(r) : "v"(lo), "v"(hi)); return r;
}
__device__ inline float rcp_fast(float x) {
    float r; asm("v_rcp_f32 %0, %1" : "=v"(r) : "v"(x)); return r;
}
__device__ inline void plswap(unsigned& a, unsigned& b) {
    auto r = __builtin_amdgcn_permlane32_swap(a, b, false, false);
    a = r[0]; b = r[1];
}
__device__ inline float2 xhalves(float x) {
    unsigned u = __builtin_bit_cast(unsigned, x);
    auto r = __builtin_amdgcn_permlane32_swap(u, u, false, false);
    return make_float2(__builtin_bit_cast(float, r[0]),
                       __builtin_bit_cast(float, r[1]));
}
// Async global->LDS, 16B/lane. LDS dest = wave-uniform base + lane*16;
// swizzle lives in the per-lane GLOBAL source address (rule 21).
__device__ inline void gl_lds16(const void* gsrc, char* ldst) {
    __builtin_amdgcn_global_load_lds(
        (const __attribute__((address_space(1))) unsigned int*)gsrc,
        (__attribute__((address_space(3))) unsigned int*)ldst,
        16, 0, 0);
}

// ---------------------------------------------------------------------------
// Kernel 0: W f32 -> bf16 (one-time). 589824 elems, 8 per thread.
// ---------------------------------------------------------------------------
__global__ __launch_bounds__(256) void convw_kernel(
    const float* __restrict__ W, short* __restrict__ Wb)
{
    int i = (blockIdx.x * 256 + threadIdx.x) * 8;
    f32x4 a = *(const f32x4*)(W + i);
    f32x4 b = *(const f32x4*)(W + i + 4);
    uint4 pk;
    pk.x = cvt_pk_bf16(a[0], a[1]); pk.y = cvt_pk_bf16(a[2], a[3]);
    pk.z = cvt_pk_bf16(b[0], b[1]); pk.w = cvt_pk_bf16(b[2], b[3]);
    *(uint4*)(Wb + i) = pk;
}

// ---------------------------------------------------------------------------
// Kernel 1 (v9): Y = relu(X @ W^T). Staged-byte-optimal blocking.
// Delivery-cap model (m13: ~10.5 B/cyc/CU): traffic = (768/BN)*75.5MB(A,f32)
// + (24576/BM)*1.18MB(W), s.t. BM*BN <= 24576 for grid>=768 (3 blocks/CU).
// Optimum (128,192): 302+226 = 528 MB -> ~80us predicted (v6 was 604->88).
// - BM=128 x BN=192, BK=64, 12 K-steps, 4 waves 2x2 (wave 64x96, acc 4x6)
// - B = Wb bf16 via gl_lds, single-buffer, source pre-swizzled c^(r&7)
// - A = X f32 reg-prefetch (8 f32x4, 1 step ahead) -> cvt_pk -> 4 swizzled
//   ds_write_b128 (v7's proven staging; conversion off the read path)
// - m97 2-barrier loop; counted vmcnt(8): drains exactly the 6 B-gl_lds,
//   A-prefetch (8 loads) stays in flight
// - LDS 48KB (A 16K + B 24K staging; 48K epilogue overlay) -> 3 blocks/CU
// ---------------------------------------------------------------------------
__global__ __launch_bounds__(256) void proj_kernel(
    const float* __restrict__ q, const float* __restrict__ k,
    const float* __restrict__ v, const short* __restrict__ Wb,
    short* __restrict__ q1, short* __restrict__ k1, short* __restrict__ v1t)
{
    __shared__ __align__(16) char lds[49152];   // A@0 16K | B@16384 24K | overlay 48K

    int p  = blockIdx.x;
    int L  = (p & 7) * 96 + (p >> 3);    // 768 blocks = 8 XCD x 96
    int mt = L >> 2, nt = L & 3;         // 192 m-tiles x 4 n-tiles
    int t  = mt >> 6;                    // 0=q,1=k,2=v (64 m-tiles each)
    int m0 = (mt & 63) << 7;
    int n0 = nt * 192;
    const float* X = (t == 0) ? q : (t == 1) ? k : v;

    int tid = threadIdx.x, lane = tid & 63, w = tid >> 6;
    int wr = w >> 1, wc = w & 1;
    int l15 = lane & 15, g = lane >> 4;

    // --- A staging (f32 reg-prefetch -> cvt -> swizzled ds_write) ---
    int tr = tid >> 1, ch = tid & 1;     // row 0..127, 32-col half
    const float* asrc = X + (size_t)(m0 + tr) * D_ + ch * 32;
    int awb[4];
    #pragma unroll
    for (int j = 0; j < 4; j++)
        awb[j] = tr * 128 + (((4 * ch + j) ^ (tr & 7)) << 4);

    // --- B staging via gl_lds: 6 insts x 32 rows (192 rows total) ---
    const short* bsrc[6];
    char*        bdst[6];
    #pragma unroll
    for (int i = 0; i < 6; i++) {
        int r = i * 32 + w * 8 + (lane >> 3);
        int c = (lane & 7) ^ (r & 7);
        bsrc[i] = Wb + (size_t)(n0 + r) * D_ + c * 8;
        bdst[i] = lds + 16384 + (i * 32 + w * 8) * 128;
    }

    f32x4 pf[8];
#define LOADA(s_) do { \
        _Pragma("unroll") \
        for (int j = 0; j < 8; j++) \
            pf[j] = *(const f32x4*)(asrc + (s_) * 64 + j * 4); \
    } while (0)

    f32x4 acc[4][6];
    #pragma unroll
    for (int m = 0; m < 4; m++)
        #pragma unroll
        for (int n = 0; n < 6; n++) acc[m][n] = (f32x4){0.f, 0.f, 0.f, 0.f};

    LOADA(0);
    for (int s = 0; s < 12; ++s) {
        __builtin_amdgcn_s_barrier();            // prev step's LDS reads done
        asm volatile("" ::: "memory");
        #pragma unroll
        for (int i = 0; i < 6; i++)
            gl_lds16(bsrc[i] + s * 64, bdst[i]);
        #pragma unroll
        for (int j = 0; j < 4; j++) {            // cvt + A writes (pf = step s)
            uint4 u;
            u.x = cvt_pk_bf16(pf[2 * j][0], pf[2 * j][1]);
            u.y = cvt_pk_bf16(pf[2 * j][2], pf[2 * j][3]);
            u.z = cvt_pk_bf16(pf[2 * j + 1][0], pf[2 * j + 1][1]);
            u.w = cvt_pk_bf16(pf[2 * j + 1][2], pf[2 * j + 1][3]);
            *(uint4*)(lds + awb[j]) = u;
        }
        if (s + 1 < 12) {
            LOADA(s + 1);                        // 8 prefetch loads in flight
            asm volatile("s_waitcnt vmcnt(8) lgkmcnt(0)" ::: "memory");
        } else {
            asm volatile("s_waitcnt vmcnt(0) lgkmcnt(0)" ::: "memory");
        }
        __builtin_amdgcn_s_barrier();            // tile ready for all waves
        asm volatile("" ::: "memory");

        #pragma unroll
        for (int kk = 0; kk < 2; kk++) {
            bf16x8 af[4], bfv[6];
            #pragma unroll
            for (int m = 0; m < 4; m++) {
                int ra = wr * 64 + m * 16 + l15;
                af[m] = *(const bf16x8*)(lds + ra * 128 +
                         ((((kk << 2) | g) ^ (ra & 7)) << 4));
            }
            #pragma unroll
            for (int n = 0; n < 6; n++) {
                int rb = wc * 96 + n * 16 + l15;
                bfv[n] = *(const bf16x8*)(lds + 16384 + rb * 128 +
                          ((((kk << 2) | g) ^ (rb & 7)) << 4));
            }
            __builtin_amdgcn_s_setprio(1);
            #pragma unroll
            for (int m = 0; m < 4; m++)
                #pragma unroll
                for (int n = 0; n < 6; n++)
                    acc[m][n] = __builtin_amdgcn_mfma_f32_16x16x32_bf16(
                        af[m], bfv[n], acc[m][n], 0, 0, 0);
            __builtin_amdgcn_s_setprio(0);
        }
    }
#undef LOADA

    // Epilogue: relu(+scale) -> bf16 -> swizzled LDS transpose -> b128 stores.
    // q/k overlay: [128 rows][24 chunks16B] stride 384B, slot = c ^ (row&7)
    // v overlay  : [192 cols][16 chunks16B] stride 256B, slot = c ^ (col&7)
    __syncthreads();
    const float sc1 = (t == 1) ? 0.18033688011112793f : 1.0f;  // 1/8*log2(e)
    #pragma unroll
    for (int m = 0; m < 4; m++)
        #pragma unroll
        for (int n = 0; n < 6; n++)
            #pragma unroll
            for (int r = 0; r < 4; r++) {
                int row = wr * 64 + m * 16 + g * 4 + r;
                int col = wc * 96 + n * 16 + l15;
                short vv = f2bf(fmaxf(acc[m][n][r], 0.f) * sc1);
                if (t == 2)   // v: transposed overlay Tv[col][row]
                    *(short*)(lds + col * 256 + (((row >> 3) ^ (col & 7)) << 4)
                              + ((row & 7) << 1)) = vv;
                else          // Ts[row][col]
                    *(short*)(lds + row * 384 + (((col >> 3) ^ (row & 7)) << 4)
                              + ((col & 7) << 1)) = vv;
            }
    __syncthreads();
    int bb2 = m0 >> 10;
    if (t == 2) {
        if (tid < 192) {
            int col = tid;                      // 192 n-cols, 16 row-chunks
            int gc = n0 + col, h = gc >> 6, dh = gc & 63;
            short* dst = v1t + (((size_t)bb2 * H_ + h) * DH_ + dh) * S_ + (m0 & 1023);
            #pragma unroll
            for (int j = 0; j < 16; j++) {
                bf16x8 val = *(const bf16x8*)(lds + col * 256 + ((j ^ (col & 7)) << 4));
                *(bf16x8*)(dst + j * 8) = val;
            }
        }
    } else {
        int row = tid >> 1, half = tid & 1;
        int m = m0 + row, ss = m & 1023;
        short* dst0 = (t ? k1 : q1);
        #pragma unroll
        for (int j = 0; j < 12; j++) {
            int cc = half * 12 + j;
            bf16x8 val = *(const bf16x8*)(lds + row * 384 + ((cc ^ (row & 7)) << 4));
            int gc = n0 + cc * 8, h = gc >> 6, dh = gc & 63;
            *(bf16x8*)(dst0 + (((size_t)bb2 * H_ + h) * S_ + ss) * DH_ + dh) = val;
        }
    }
}

// ---------------------------------------------------------------------------
// Kernel 2 (v5): flash attention, swapped-QK^T 32x32x16, block-cooperative
// LDS-staged K/V (unchanged from round 6 -- passing, fast).
// ---------------------------------------------------------------------------
__global__ __launch_bounds__(256, 3) void attn_kernel(
    const short* __restrict__ q1, const short* __restrict__ k1,
    const short* __restrict__ v1t, float* __restrict__ out)
{
    __shared__ short Klds[2][4096];
    __shared__ short Vlds[2][4096];
    __shared__ float lsum_lds[4][32];

    int d    = blockIdx.x;
    int head = (d & 7) + ((d >> 6) << 3);
    int qi   = (d >> 3) & 7;
    int bb   = head / H_, hh = head % H_;

    int tid = threadIdx.x, lane = tid & 63, w = tid >> 6;
    int l31 = lane & 31, hi = lane >> 5;
    int qbase = (qi * 4 + w) * 32;

    const short* Qp = q1  + (size_t)head * S_ * DH_;
    const short* Kp = k1  + (size_t)head * S_ * DH_;
    const short* Vp = v1t + (size_t)head * DH_ * S_;

    int sr = tid >> 2, sc = tid & 3;
    int swz0 = sr * 128 + ((sc       ^ (sr & 7)) << 4);
    int swz1 = sr * 128 + (((sc + 4) ^ (sr & 7)) << 4);

    bf16x8 stK0, stK1, stV0, stV1;

#define LOADST(kvb) do { \
        const short* _kg = Kp + (size_t)((kvb) + sr) * DH_; \
        const short* _vg = Vp + (size_t)sr * S_ + (kvb); \
        stK0 = *(const bf16x8*)(_kg + sc * 8); \
        stK1 = *(const bf16x8*)(_kg + (sc + 4) * 8); \
        stV0 = *(const bf16x8*)(_vg + sc * 8); \
        stV1 = *(const bf16x8*)(_vg + (sc + 4) * 8); \
    } while (0)
#define WRITEST(buf) do { \
        char* _kb = (char*)&Klds[buf][0]; \
        char* _vb = (char*)&Vlds[buf][0]; \
        *(bf16x8*)(_kb + swz0) = stK0; \
        *(bf16x8*)(_kb + swz1) = stK1; \
        *(bf16x8*)(_vb + swz0) = stV0; \
        *(bf16x8*)(_vb + swz1) = stV1; \
    } while (0)

    bf16x8 qf[4];
    #pragma unroll
    for (int kb = 0; kb < 4; kb++)
        qf[kb] = *(const bf16x8*)(Qp + (size_t)(qbase + l31) * DH_ + kb * 16 + hi * 8);

    f32x16 o0, o1;
    #pragma unroll
    for (int r = 0; r < 16; r++) { o0[r] = 0.f; o1[r] = 0.f; }
    float mreg = -1e30f, lsum = 0.f;

    int xk = l31 & 7;

    auto subtile = [&](int cur, int j) {
        const char* Kt = (const char*)&Klds[cur][0];
        const char* Vt = (const char*)&Vlds[cur][0];
        int rK = (32 * j + l31) * 128;
        bf16x8 kf0 = *(const bf16x8*)(Kt + rK + (((0 + hi) ^ xk) << 4));
        bf16x8 kf1 = *(const bf16x8*)(Kt + rK + (((2 + hi) ^ xk) << 4));
        bf16x8 kf2 = *(const bf16x8*)(Kt + rK + (((4 + hi) ^ xk) << 4));
        bf16x8 kf3 = *(const bf16x8*)(Kt + rK + (((6 + hi) ^ xk) << 4));
        int rV0 = l31 * 128, rV1 = (32 + l31) * 128;
        int s0 = ((4 * j + hi) ^ xk) << 4, s1 = ((4 * j + 2 + hi) ^ xk) << 4;
        bf16x8 vf00 = *(const bf16x8*)(Vt + rV0 + s0);
        bf16x8 vf01 = *(const bf16x8*)(Vt + rV0 + s1);
        bf16x8 vf10 = *(const bf16x8*)(Vt + rV1 + s0);
        bf16x8 vf11 = *(const bf16x8*)(Vt + rV1 + s1);

        f32x16 s;
        #pragma unroll
        for (int r = 0; r < 16; r++) s[r] = 0.f;
        __builtin_amdgcn_s_setprio(1);
        s = __builtin_amdgcn_mfma_f32_32x32x16_bf16(kf0, qf[0], s, 0, 0, 0);
        s = __builtin_amdgcn_mfma_f32_32x32x16_bf16(kf1, qf[1], s, 0, 0, 0);
        s = __builtin_amdgcn_mfma_f32_32x32x16_bf16(kf2, qf[2], s, 0, 0, 0);
        s = __builtin_amdgcn_mfma_f32_32x32x16_bf16(kf3, qf[3], s, 0, 0, 0);
        __builtin_amdgcn_s_setprio(0);

        float t0 = fmaxf(s[0], s[1]),   t1 = fmaxf(s[2], s[3]);
        float t2 = fmaxf(s[4], s[5]),   t3 = fmaxf(s[6], s[7]);
        float t4 = fmaxf(s[8], s[9]),   t5 = fmaxf(s[10], s[11]);
        float t6 = fmaxf(s[12], s[13]), t7 = fmaxf(s[14], s[15]);
        float u0 = fmaxf(t0, t1), u1 = fmaxf(t2, t3);
        float u2 = fmaxf(t4, t5), u3 = fmaxf(t6, t7);
        float pmax = fmaxf(fmaxf(u0, u1), fmaxf(u2, u3));
        float2 ph = xhalves(pmax);
        pmax = fmaxf(ph.x, ph.y);

        if (!__all(pmax <= mreg + 8.f)) {
            float mn = fmaxf(mreg, pmax);
            float sc_ = exp2_fast(mreg - mn);
            mreg = mn; lsum *= sc_;
            if (hi == 0) lsum_lds[w][l31] = sc_;
            asm volatile("s_waitcnt lgkmcnt(0)" ::: "memory");
            #pragma unroll
            for (int r = 0; r < 16; r++) {
                int crow = (r & 3) + ((r >> 2) << 3) + (hi << 2);
                float srw = lsum_lds[w][crow];
                o0[r] *= srw; o1[r] *= srw;
            }
        }

        #pragma unroll
        for (int r = 0; r < 16; r++) s[r] = exp2_fast(s[r] - mreg);

        float a0 = s[0] + s[1],   a1 = s[2] + s[3];
        float a2 = s[4] + s[5],   a3 = s[6] + s[7];
        float a4 = s[8] + s[9],   a5 = s[10] + s[11];
        float a6 = s[12] + s[13], a7 = s[14] + s[15];
        float rsum = ((a0 + a1) + (a2 + a3)) + ((a4 + a5) + (a6 + a7));
        float2 rh = xhalves(rsum);
        lsum += rh.x + rh.y;

        unsigned c0 = cvt_pk_bf16(s[0], s[1]);
        unsigned c1 = cvt_pk_bf16(s[2], s[3]);
        unsigned c2 = cvt_pk_bf16(s[4], s[5]);
        unsigned c3 = cvt_pk_bf16(s[6], s[7]);
        unsigned c4 = cvt_pk_bf16(s[8], s[9]);
        unsigned c5 = cvt_pk_bf16(s[10], s[11]);
        unsigned c6 = cvt_pk_bf16(s[12], s[13]);
        unsigned c7 = cvt_pk_bf16(s[14], s[15]);
        plswap(c0, c2);
        plswap(c1, c3);
        plswap(c4, c6);
        plswap(c5, c7);

        union U { unsigned u[4]; bf16x8 v; };
        U f0, f1;
        f0.u[0] = c0; f0.u[1] = c1; f0.u[2] = c2; f0.u[3] = c3;
        f1.u[0] = c4; f1.u[1] = c5; f1.u[2] = c6; f1.u[3] = c7;

        __builtin_amdgcn_s_setprio(1);
        o0 = __builtin_amdgcn_mfma_f32_32x32x16_bf16(f0.v, vf00, o0, 0, 0, 0);
        o0 = __builtin_amdgcn_mfma_f32_32x32x16_bf16(f1.v, vf01, o0, 0, 0, 0);
        o1 = __builtin_amdgcn_mfma_f32_32x32x16_bf16(f0.v, vf10, o1, 0, 0, 0);
        o1 = __builtin_amdgcn_mfma_f32_32x32x16_bf16(f1.v, vf11, o1, 0, 0, 0);
        __builtin_amdgcn_s_setprio(0);
    };

    LOADST(0);
    WRITEST(0);
    LOADST(64);
    asm volatile("s_waitcnt lgkmcnt(0)" ::: "memory");
    __builtin_amdgcn_s_barrier();
    asm volatile("" ::: "memory");

    int cur = 0;
    for (int t = 0; t < 16; t++) {
        if (t < 15) {
            WRITEST(cur ^ 1);
            if (t < 14) LOADST((t + 2) * 64);
        }
        subtile(cur, 0);
        subtile(cur, 1);
        if (t < 15) {
            asm volatile("" ::: "memory");
            asm volatile("s_waitcnt lgkmcnt(0)" ::: "memory");
            __builtin_amdgcn_s_barrier();
            asm volatile("" ::: "memory");
        }
        cur ^= 1;
    }
#undef LOADST
#undef WRITEST

    if (hi == 0) lsum_lds[w][l31] = lsum;
    asm volatile("s_waitcnt lgkmcnt(0)" ::: "memory");
    #pragma unroll
    for (int r = 0; r < 16; r++) {
        int crow = (r & 3) + ((r >> 2) << 3) + (hi << 2);
        float inv = rcp_fast(lsum_lds[w][crow]);
        float* op = out + ((size_t)(bb * S_ + qbase + crow)) * D_ + hh * DH_ + l31;
        op[0]  = o0[r] * inv;
        op[32] = o1[r] * inv;
    }
}

// ---------------------------------------------------------------------------
// Kernel 3 (v2): y = LN(2*out + q) * gamma + beta; 192 thr/row, f32x4 loads.
// ---------------------------------------------------------------------------
__global__ __launch_bounds__(192) void ln_kernel(
    const float* __restrict__ qin, const float* __restrict__ gamma,
    const float* __restrict__ beta, float* __restrict__ out)
{
    int row = blockIdx.x;
    int tid = threadIdx.x;
    size_t base = (size_t)row * D_ + tid * 4;

    f32x4 o  = *(const f32x4*)(out + base);
    f32x4 qv = *(const f32x4*)(qin + base);
    f32x4 x;
    float sum = 0.f, sq = 0.f;
    #pragma unroll
    for (int i = 0; i < 4; i++) {
        x[i] = 2.f * o[i] + qv[i];
        sum += x[i];
        sq  += x[i] * x[i];
    }
    #pragma unroll
    for (int msk = 1; msk < 64; msk <<= 1) {
        sum += __shfl_xor(sum, msk);
        sq  += __shfl_xor(sq, msk);
    }
    __shared__ float s1[3], s2[3];
    if ((tid & 63) == 0) { s1[tid >> 6] = sum; s2[tid >> 6] = sq; }
    __syncthreads();
    sum = s1[0] + s1[1] + s1[2];
    sq  = s2[0] + s2[1] + s2[2];
    float mu   = sum * (1.f / D_);
    float var  = sq * (1.f / D_) - mu * mu;
    float rstd = rsqrtf(var + 1e-5f);
    f32x4 g = *(const f32x4*)(gamma + tid * 4);
    f32x4 b = *(const f32x4*)(beta + tid * 4);
    f32x4 y;
    #pragma unroll
    for (int i = 0; i < 4; i++)
        y[i] = (x[i] - mu) * rstd * g[i] + b[i];
    *(f32x4*)(out + base) = y;
}

// ---------------------------------------------------------------------------
extern "C" void kernel_launch(void* const* d_in, const int* in_sizes, int n_in,
                              void* d_out, int out_size, void* d_ws, size_t ws_size,
                              hipStream_t stream)
{
    const float* q     = (const float*)d_in[0];
    const float* k     = (const float*)d_in[1];
    const float* v     = (const float*)d_in[2];
    const float* W     = (const float*)d_in[3];
    const float* gamma = (const float*)d_in[4];
    const float* beta  = (const float*)d_in[5];

    size_t per = (size_t)B_ * H_ * S_ * DH_;   // 6291456
    short* q1  = (short*)d_ws;
    short* k1  = q1 + per;
    short* v1t = k1 + per;
    short* Wb  = v1t + per;                    // +1.18 MB
    float* out = (float*)d_out;

    convw_kernel<<<dim3(288), dim3(256), 0, stream>>>(W, Wb);
    // 192 m-tiles (3 inputs x 64) x 4 n-tiles = 768 blocks
    proj_kernel<<<dim3(768), dim3(256), 0, stream>>>(q, k, v, Wb, q1, k1, v1t);
    attn_kernel<<<dim3(768), dim3(256), 0, stream>>>(q1, k1, v1t, out);
    ln_kernel<<<dim3(B_ * S_), dim3(192), 0, stream>>>(q, gamma, beta, out);
}

// Round 14
// 117.179 us; speedup vs baseline: 1.4953x; 1.4953x over previous
//
#include <hip/hip_runtime.h>
#include <hip/hip_bf16.h>

// Problem constants (B,S,D,H fixed by setup_inputs)
#define B_  8
#define S_  1024
#define D_  768
#define H_  12
#define DH_ 64

typedef __attribute__((ext_vector_type(8))) short bf16x8;
typedef __attribute__((ext_vector_type(4))) float f32x4;
typedef __attribute__((ext_vector_type(16))) float f32x16;

__device__ inline short f2bf(float f) {
    unsigned u = __builtin_bit_cast(unsigned, f);
    u = (u + 0x7fffu + ((u >> 16) & 1u)) >> 16;   // RNE
    return (short)u;
}
__device__ inline float exp2_fast(float x) {
    float r; asm("v_exp_f32 %0, %1" : "=v"(r) : "v"(x)); return r;
}
__device__ inline unsigned cvt_pk_bf16(float lo, float hi) {
    unsigned r; asm("v_cvt_pk_bf16_f32 %0, %1, %2" : "=v"(r) : "v"(lo), "v"(hi)); return r;
}
__device__ inline float rcp_fast(float x) {
    float r; asm("v_rcp_f32 %0, %1" : "=v"(r) : "v"(x)); return r;
}
__device__ inline void plswap(unsigned& a, unsigned& b) {
    auto r = __builtin_amdgcn_permlane32_swap(a, b, false, false);
    a = r[0]; b = r[1];
}
__device__ inline float2 xhalves(float x) {
    unsigned u = __builtin_bit_cast(unsigned, x);
    auto r = __builtin_amdgcn_permlane32_swap(u, u, false, false);
    return make_float2(__builtin_bit_cast(float, r[0]),
                       __builtin_bit_cast(float, r[1]));
}
// Async global->LDS, 16B/lane. LDS dest = wave-uniform base + lane*16;
// swizzle lives in the per-lane GLOBAL source address (rule 21).
__device__ inline void gl_lds16(const void* gsrc, char* ldst) {
    __builtin_amdgcn_global_load_lds(
        (const __attribute__((address_space(1))) unsigned int*)gsrc,
        (__attribute__((address_space(3))) unsigned int*)ldst,
        16, 0, 0);
}

// ---------------------------------------------------------------------------
// Kernel 0: W f32 -> bf16 (one-time; makes proj's B-stream half-width and
// gl_lds-stageable). 589824 elems, 8 per thread.
// ---------------------------------------------------------------------------
__global__ __launch_bounds__(256) void convw_kernel(
    const float* __restrict__ W, short* __restrict__ Wb)
{
    int i = (blockIdx.x * 256 + threadIdx.x) * 8;
    f32x4 a = *(const f32x4*)(W + i);
    f32x4 b = *(const f32x4*)(W + i + 4);
    uint4 pk;
    pk.x = cvt_pk_bf16(a[0], a[1]); pk.y = cvt_pk_bf16(a[2], a[3]);
    pk.z = cvt_pk_bf16(b[0], b[1]); pk.w = cvt_pk_bf16(b[2], b[3]);
    *(uint4*)(Wb + i) = pk;
}

// ---------------------------------------------------------------------------
// Kernel 1 (v6): Y = relu(X @ W^T). Traffic-restructured (best measured: 88us):
// - block = 64 m-rows x 384 n-cols (BN=384 -> A-panels read 2x not 6x)
// - 512 threads / 8 waves; wave w owns cols [w*48, w*48+48) (4x3 frags)
// - B operand = pre-converted Wb (bf16) staged via gl_lds (24KB/step)
// - A operand = X f32 staged via gl_lds (8KB/step), cvt_pk fused in frag read
// - double-buffered, COUNTED vmcnt(4) per step (T4: never drain to 0)
// - LDS exactly 64KB -> 2 blocks/CU; XCD swizzle pairs the 2 n-blocks of
//   each m-panel on one XCD (A panel shared via its L2)
// ---------------------------------------------------------------------------
__global__ __launch_bounds__(512) void proj_kernel(
    const float* __restrict__ q, const float* __restrict__ k,
    const float* __restrict__ v, const short* __restrict__ Wb,
    short* __restrict__ q1, short* __restrict__ k1, short* __restrict__ v1t)
{
    __shared__ __align__(16) char lds[65536];
    // X bufs at 0, 8192      : [64 rows][8 chunks16B], slot = c ^ (row&7)
    // W bufs at 16384, 40960 : [384 rows][4 chunks16B], slot = c ^ ((row>>1)&3)

    int p  = blockIdx.x;
    int L  = (p & 7) * 96 + (p >> 3);        // 768 blocks = 8 XCD x 96
    int mt = L >> 1, nb = L & 1;
    int t  = mt >> 7;                        // 128 m-blocks per input
    int m0 = (mt & 127) << 6;
    int n0 = nb * 384;
    const float* X = (t == 0) ? q : (t == 1) ? k : v;

    int tid = threadIdx.x, lane = tid & 63, w = tid >> 6;   // w 0..7
    int l15 = lane & 15, g = lane >> 4;

    // staging source addresses (per-lane, pre-swizzled)
    int xrow = w * 8 + (lane >> 3), xc = lane & 7;
    const float* xsrc = X + (size_t)(m0 + xrow) * D_ + ((xc ^ (xrow & 7)) << 2);
    char* xdst = lds + w * 1024;
    int wrow0 = w * 48 + (lane >> 2), wc = lane & 3;
    int wrow1 = wrow0 + 16, wrow2 = wrow0 + 32;
    const short* wsrc0 = Wb + (size_t)(n0 + wrow0) * D_ + ((wc ^ ((wrow0 >> 1) & 3)) << 3);
    const short* wsrc1 = Wb + (size_t)(n0 + wrow1) * D_ + ((wc ^ ((wrow1 >> 1) & 3)) << 3);
    const short* wsrc2 = Wb + (size_t)(n0 + wrow2) * D_ + ((wc ^ ((wrow2 >> 1) & 3)) << 3);
    char* wdst = lds + 16384 + w * 3072;

#define ISSUE(s_, b_) do { int _ko = (s_) * 32; \
        gl_lds16(xsrc + _ko, xdst + (b_) * 8192); \
        gl_lds16(wsrc0 + _ko, wdst + (b_) * 24576); \
        gl_lds16(wsrc1 + _ko, wdst + (b_) * 24576 + 1024); \
        gl_lds16(wsrc2 + _ko, wdst + (b_) * 24576 + 2048); \
    } while (0)

    f32x4 acc[4][3];
    #pragma unroll
    for (int m = 0; m < 4; m++)
        #pragma unroll
        for (int n = 0; n < 3; n++) acc[m][n] = (f32x4){0.f, 0.f, 0.f, 0.f};

    ISSUE(0, 0);
    for (int s = 0; s < 24; ++s) {
        __builtin_amdgcn_s_barrier();            // reads of target buf done
        asm volatile("" ::: "memory");
        if (s + 1 < 24) {
            ISSUE(s + 1, (s + 1) & 1);
            asm volatile("s_waitcnt vmcnt(4)" ::: "memory");   // step-s landed
        } else {
            asm volatile("s_waitcnt vmcnt(0)" ::: "memory");
        }
        __builtin_amdgcn_s_barrier();            // all waves' loads landed
        asm volatile("" ::: "memory");

        const char* Xb = lds + (s & 1) * 8192;
        const char* Wp = lds + 16384 + (s & 1) * 24576;
        bf16x8 af[4];
        #pragma unroll
        for (int m = 0; m < 4; m++) {
            int r = m * 16 + l15;
            const char* rp = Xb + r * 128;
            f32x4 lo = *(const f32x4*)(rp + (((2 * g)     ^ (r & 7)) << 4));
            f32x4 hi = *(const f32x4*)(rp + (((2 * g + 1) ^ (r & 7)) << 4));
            uint4 pk;
            pk.x = cvt_pk_bf16(lo[0], lo[1]); pk.y = cvt_pk_bf16(lo[2], lo[3]);
            pk.z = cvt_pk_bf16(hi[0], hi[1]); pk.w = cvt_pk_bf16(hi[2], hi[3]);
            af[m] = __builtin_bit_cast(bf16x8, pk);
        }
        bf16x8 bfv[3];
        #pragma unroll
        for (int n = 0; n < 3; n++) {
            int r = w * 48 + n * 16 + l15;
            bfv[n] = *(const bf16x8*)(Wp + r * 64 + ((g ^ ((r >> 1) & 3)) << 4));
        }
        __builtin_amdgcn_s_setprio(1);
        #pragma unroll
        for (int m = 0; m < 4; m++)
            #pragma unroll
            for (int n = 0; n < 3; n++)
                acc[m][n] = __builtin_amdgcn_mfma_f32_16x16x32_bf16(
                    af[m], bfv[n], acc[m][n], 0, 0, 0);
        __builtin_amdgcn_s_setprio(0);
    }
#undef ISSUE

    // Epilogue: relu(+scale) -> bf16 -> swizzled LDS transpose -> b128 stores.
    // q/k overlay: [64 rows][48 chunks16B], slot = ch ^ (row&7)  (48KB)
    // v overlay  : [384 rows][8 chunks16B], slot = ch ^ (row&7)  (48KB)
    __syncthreads();
    const float sc1 = (t == 1) ? 0.18033688011112793f : 1.0f;  // 1/8*log2(e)
    #pragma unroll
    for (int m = 0; m < 4; m++)
        #pragma unroll
        for (int n = 0; n < 3; n++)
            #pragma unroll
            for (int r = 0; r < 4; r++) {
                int row = m * 16 + g * 4 + r;
                int col = w * 48 + n * 16 + l15;
                short vv = f2bf(fmaxf(acc[m][n][r], 0.f) * sc1);
                if (t == 2)   // v stored transposed: Ts[col 0..383][row 0..63]
                    *(short*)(lds + col * 128 + (((row >> 3) ^ (col & 7)) << 4)
                              + ((row & 7) << 1)) = vv;
                else          // Ts[row 0..63][col 0..383]
                    *(short*)(lds + row * 768 + (((col >> 3) ^ (row & 7)) << 4)
                              + ((col & 7) << 1)) = vv;
            }
    __syncthreads();
    int bb2 = m0 >> 10;
    if (t == 2) {
        #pragma unroll
        for (int j = 0; j < 6; j++) {
            int c = tid * 6 + j;          // 3072 chunks: vr = c>>3, ch = c&7
            int vr = c >> 3, ch = c & 7;
            bf16x8 val = *(const bf16x8*)(lds + vr * 128 + ((ch ^ (vr & 7)) << 4));
            int gc = n0 + vr, h = gc >> 6, dh = gc & 63;
            *(bf16x8*)(v1t + (((size_t)bb2 * H_ + h) * DH_ + dh) * S_
                       + (m0 & 1023) + ch * 8) = val;
        }
    } else {
        short* dst0 = t ? k1 : q1;
        #pragma unroll
        for (int j = 0; j < 6; j++) {
            int c = tid * 6 + j;          // 3072 chunks: row = c/48, ch = c%48
            int row = c / 48, ch = c % 48;
            bf16x8 val = *(const bf16x8*)(lds + row * 768 + ((ch ^ (row & 7)) << 4));
            int m = m0 + row, ss = m & 1023;
            int gc = n0 + ch * 8, h = gc >> 6, dh = gc & 63;
            *(bf16x8*)(dst0 + (((size_t)bb2 * H_ + h) * S_ + ss) * DH_ + dh) = val;
        }
    }
}

// ---------------------------------------------------------------------------
// Kernel 2 (v5): flash attention, swapped-QK^T 32x32x16, block-cooperative
// LDS-staged K/V (unchanged from round 6 -- passing, fast).
// ---------------------------------------------------------------------------
__global__ __launch_bounds__(256, 3) void attn_kernel(
    const short* __restrict__ q1, const short* __restrict__ k1,
    const short* __restrict__ v1t, float* __restrict__ out)
{
    __shared__ short Klds[2][4096];
    __shared__ short Vlds[2][4096];
    __shared__ float lsum_lds[4][32];

    int d    = blockIdx.x;
    int head = (d & 7) + ((d >> 6) << 3);
    int qi   = (d >> 3) & 7;
    int bb   = head / H_, hh = head % H_;

    int tid = threadIdx.x, lane = tid & 63, w = tid >> 6;
    int l31 = lane & 31, hi = lane >> 5;
    int qbase = (qi * 4 + w) * 32;

    const short* Qp = q1  + (size_t)head * S_ * DH_;
    const short* Kp = k1  + (size_t)head * S_ * DH_;
    const short* Vp = v1t + (size_t)head * DH_ * S_;

    int sr = tid >> 2, sc = tid & 3;
    int swz0 = sr * 128 + ((sc       ^ (sr & 7)) << 4);
    int swz1 = sr * 128 + (((sc + 4) ^ (sr & 7)) << 4);

    bf16x8 stK0, stK1, stV0, stV1;

#define LOADST(kvb) do { \
        const short* _kg = Kp + (size_t)((kvb) + sr) * DH_; \
        const short* _vg = Vp + (size_t)sr * S_ + (kvb); \
        stK0 = *(const bf16x8*)(_kg + sc * 8); \
        stK1 = *(const bf16x8*)(_kg + (sc + 4) * 8); \
        stV0 = *(const bf16x8*)(_vg + sc * 8); \
        stV1 = *(const bf16x8*)(_vg + (sc + 4) * 8); \
    } while (0)
#define WRITEST(buf) do { \
        char* _kb = (char*)&Klds[buf][0]; \
        char* _vb = (char*)&Vlds[buf][0]; \
        *(bf16x8*)(_kb + swz0) = stK0; \
        *(bf16x8*)(_kb + swz1) = stK1; \
        *(bf16x8*)(_vb + swz0) = stV0; \
        *(bf16x8*)(_vb + swz1) = stV1; \
    } while (0)

    bf16x8 qf[4];
    #pragma unroll
    for (int kb = 0; kb < 4; kb++)
        qf[kb] = *(const bf16x8*)(Qp + (size_t)(qbase + l31) * DH_ + kb * 16 + hi * 8);

    f32x16 o0, o1;
    #pragma unroll
    for (int r = 0; r < 16; r++) { o0[r] = 0.f; o1[r] = 0.f; }
    float mreg = -1e30f, lsum = 0.f;

    int xk = l31 & 7;

    auto subtile = [&](int cur, int j) {
        const char* Kt = (const char*)&Klds[cur][0];
        const char* Vt = (const char*)&Vlds[cur][0];
        int rK = (32 * j + l31) * 128;
        bf16x8 kf0 = *(const bf16x8*)(Kt + rK + (((0 + hi) ^ xk) << 4));
        bf16x8 kf1 = *(const bf16x8*)(Kt + rK + (((2 + hi) ^ xk) << 4));
        bf16x8 kf2 = *(const bf16x8*)(Kt + rK + (((4 + hi) ^ xk) << 4));
        bf16x8 kf3 = *(const bf16x8*)(Kt + rK + (((6 + hi) ^ xk) << 4));
        int rV0 = l31 * 128, rV1 = (32 + l31) * 128;
        int s0 = ((4 * j + hi) ^ xk) << 4, s1 = ((4 * j + 2 + hi) ^ xk) << 4;
        bf16x8 vf00 = *(const bf16x8*)(Vt + rV0 + s0);
        bf16x8 vf01 = *(const bf16x8*)(Vt + rV0 + s1);
        bf16x8 vf10 = *(const bf16x8*)(Vt + rV1 + s0);
        bf16x8 vf11 = *(const bf16x8*)(Vt + rV1 + s1);

        f32x16 s;
        #pragma unroll
        for (int r = 0; r < 16; r++) s[r] = 0.f;
        __builtin_amdgcn_s_setprio(1);
        s = __builtin_amdgcn_mfma_f32_32x32x16_bf16(kf0, qf[0], s, 0, 0, 0);
        s = __builtin_amdgcn_mfma_f32_32x32x16_bf16(kf1, qf[1], s, 0, 0, 0);
        s = __builtin_amdgcn_mfma_f32_32x32x16_bf16(kf2, qf[2], s, 0, 0, 0);
        s = __builtin_amdgcn_mfma_f32_32x32x16_bf16(kf3, qf[3], s, 0, 0, 0);
        __builtin_amdgcn_s_setprio(0);

        float t0 = fmaxf(s[0], s[1]),   t1 = fmaxf(s[2], s[3]);
        float t2 = fmaxf(s[4], s[5]),   t3 = fmaxf(s[6], s[7]);
        float t4 = fmaxf(s[8], s[9]),   t5 = fmaxf(s[10], s[11]);
        float t6 = fmaxf(s[12], s[13]), t7 = fmaxf(s[14], s[15]);
        float u0 = fmaxf(t0, t1), u1 = fmaxf(t2, t3);
        float u2 = fmaxf(t4, t5), u3 = fmaxf(t6, t7);
        float pmax = fmaxf(fmaxf(u0, u1), fmaxf(u2, u3));
        float2 ph = xhalves(pmax);
        pmax = fmaxf(ph.x, ph.y);

        if (!__all(pmax <= mreg + 8.f)) {
            float mn = fmaxf(mreg, pmax);
            float sc_ = exp2_fast(mreg - mn);
            mreg = mn; lsum *= sc_;
            if (hi == 0) lsum_lds[w][l31] = sc_;
            asm volatile("s_waitcnt lgkmcnt(0)" ::: "memory");
            #pragma unroll
            for (int r = 0; r < 16; r++) {
                int crow = (r & 3) + ((r >> 2) << 3) + (hi << 2);
                float srw = lsum_lds[w][crow];
                o0[r] *= srw; o1[r] *= srw;
            }
        }

        #pragma unroll
        for (int r = 0; r < 16; r++) s[r] = exp2_fast(s[r] - mreg);

        float a0 = s[0] + s[1],   a1 = s[2] + s[3];
        float a2 = s[4] + s[5],   a3 = s[6] + s[7];
        float a4 = s[8] + s[9],   a5 = s[10] + s[11];
        float a6 = s[12] + s[13], a7 = s[14] + s[15];
        float rsum = ((a0 + a1) + (a2 + a3)) + ((a4 + a5) + (a6 + a7));
        float2 rh = xhalves(rsum);
        lsum += rh.x + rh.y;

        unsigned c0 = cvt_pk_bf16(s[0], s[1]);
        unsigned c1 = cvt_pk_bf16(s[2], s[3]);
        unsigned c2 = cvt_pk_bf16(s[4], s[5]);
        unsigned c3 = cvt_pk_bf16(s[6], s[7]);
        unsigned c4 = cvt_pk_bf16(s[8], s[9]);
        unsigned c5 = cvt_pk_bf16(s[10], s[11]);
        unsigned c6 = cvt_pk_bf16(s[12], s[13]);
        unsigned c7 = cvt_pk_bf16(s[14], s[15]);
        plswap(c0, c2);
        plswap(c1, c3);
        plswap(c4, c6);
        plswap(c5, c7);

        union U { unsigned u[4]; bf16x8 v; };
        U f0, f1;
        f0.u[0] = c0; f0.u[1] = c1; f0.u[2] = c2; f0.u[3] = c3;
        f1.u[0] = c4; f1.u[1] = c5; f1.u[2] = c6; f1.u[3] = c7;

        __builtin_amdgcn_s_setprio(1);
        o0 = __builtin_amdgcn_mfma_f32_32x32x16_bf16(f0.v, vf00, o0, 0, 0, 0);
        o0 = __builtin_amdgcn_mfma_f32_32x32x16_bf16(f1.v, vf01, o0, 0, 0, 0);
        o1 = __builtin_amdgcn_mfma_f32_32x32x16_bf16(f0.v, vf10, o1, 0, 0, 0);
        o1 = __builtin_amdgcn_mfma_f32_32x32x16_bf16(f1.v, vf11, o1, 0, 0, 0);
        __builtin_amdgcn_s_setprio(0);
    };

    LOADST(0);
    WRITEST(0);
    LOADST(64);
    asm volatile("s_waitcnt lgkmcnt(0)" ::: "memory");
    __builtin_amdgcn_s_barrier();
    asm volatile("" ::: "memory");

    int cur = 0;
    for (int t = 0; t < 16; t++) {
        if (t < 15) {
            WRITEST(cur ^ 1);
            if (t < 14) LOADST((t + 2) * 64);
        }
        subtile(cur, 0);
        subtile(cur, 1);
        if (t < 15) {
            asm volatile("" ::: "memory");
            asm volatile("s_waitcnt lgkmcnt(0)" ::: "memory");
            __builtin_amdgcn_s_barrier();
            asm volatile("" ::: "memory");
        }
        cur ^= 1;
    }
#undef LOADST
#undef WRITEST

    if (hi == 0) lsum_lds[w][l31] = lsum;
    asm volatile("s_waitcnt lgkmcnt(0)" ::: "memory");
    #pragma unroll
    for (int r = 0; r < 16; r++) {
        int crow = (r & 3) + ((r >> 2) << 3) + (hi << 2);
        float inv = rcp_fast(lsum_lds[w][crow]);
        float* op = out + ((size_t)(bb * S_ + qbase + crow)) * D_ + hh * DH_ + l31;
        op[0]  = o0[r] * inv;
        op[32] = o1[r] * inv;
    }
}

// ---------------------------------------------------------------------------
// Kernel 3 (v2): y = LN(2*out + q) * gamma + beta; 192 thr/row, f32x4 loads.
// ---------------------------------------------------------------------------
__global__ __launch_bounds__(192) void ln_kernel(
    const float* __restrict__ qin, const float* __restrict__ gamma,
    const float* __restrict__ beta, float* __restrict__ out)
{
    int row = blockIdx.x;
    int tid = threadIdx.x;
    size_t base = (size_t)row * D_ + tid * 4;

    f32x4 o  = *(const f32x4*)(out + base);
    f32x4 qv = *(const f32x4*)(qin + base);
    f32x4 x;
    float sum = 0.f, sq = 0.f;
    #pragma unroll
    for (int i = 0; i < 4; i++) {
        x[i] = 2.f * o[i] + qv[i];
        sum += x[i];
        sq  += x[i] * x[i];
    }
    #pragma unroll
    for (int msk = 1; msk < 64; msk <<= 1) {
        sum += __shfl_xor(sum, msk);
        sq  += __shfl_xor(sq, msk);
    }
    __shared__ float s1[3], s2[3];
    if ((tid & 63) == 0) { s1[tid >> 6] = sum; s2[tid >> 6] = sq; }
    __syncthreads();
    sum = s1[0] + s1[1] + s1[2];
    sq  = s2[0] + s2[1] + s2[2];
    float mu   = sum * (1.f / D_);
    float var  = sq * (1.f / D_) - mu * mu;
    float rstd = rsqrtf(var + 1e-5f);
    f32x4 g = *(const f32x4*)(gamma + tid * 4);
    f32x4 b = *(const f32x4*)(beta + tid * 4);
    f32x4 y;
    #pragma unroll
    for (int i = 0; i < 4; i++)
        y[i] = (x[i] - mu) * rstd * g[i] + b[i];
    *(f32x4*)(out + base) = y;
}

// ---------------------------------------------------------------------------
extern "C" void kernel_launch(void* const* d_in, const int* in_sizes, int n_in,
                              void* d_out, int out_size, void* d_ws, size_t ws_size,
                              hipStream_t stream)
{
    const float* q     = (const float*)d_in[0];
    const float* k     = (const float*)d_in[1];
    const float* v     = (const float*)d_in[2];
    const float* W     = (const float*)d_in[3];
    const float* gamma = (const float*)d_in[4];
    const float* beta  = (const float*)d_in[5];

    size_t per = (size_t)B_ * H_ * S_ * DH_;   // 6291456
    short* q1  = (short*)d_ws;
    short* k1  = q1 + per;
    short* v1t = k1 + per;
    short* Wb  = v1t + per;                    // +1.18 MB (total ~38.9 MB)
    float* out = (float*)d_out;

    convw_kernel<<<dim3(288), dim3(256), 0, stream>>>(W, Wb);
    // 384 m-blocks (3 inputs x 128) x 2 n-blocks = 768 blocks, 512 threads
    proj_kernel<<<dim3(768), dim3(512), 0, stream>>>(q, k, v, Wb, q1, k1, v1t);
    attn_kernel<<<dim3(768), dim3(256), 0, stream>>>(q1, k1, v1t, out);
    ln_kernel<<<dim3(B_ * S_), dim3(192), 0, stream>>>(q, gamma, beta, out);
}

// Round 15
// 109.610 us; speedup vs baseline: 1.5985x; 1.0690x over previous
//
#include <hip/hip_runtime.h>
#include <hip/hip_bf16.h>

// Problem constants (B,S,D,H fixed by setup_inputs)
#define B_  8
#define S_  1024
#define D_  768
#define H_  12
#define DH_ 64

typedef __attribute__((ext_vector_type(8))) short bf16x8;
typedef __attribute__((ext_vector_type(4))) float f32x4;
typedef __attribute__((ext_vector_type(16))) float f32x16;

__device__ inline short f2bf(float f) {
    unsigned u = __builtin_bit_cast(unsigned, f);
    u = (u + 0x7fffu + ((u >> 16) & 1u)) >> 16;   // RNE
    return (short)u;
}
__device__ inline float exp2_fast(float x) {
    float r; asm("v_exp_f32 %0, %1" : "=v"(r) : "v"(x)); return r;
}
__device__ inline unsigned cvt_pk_bf16(float lo, float hi) {
    unsigned r; asm("v_cvt_pk_bf16_f32 %0, %1, %2" : "=v"(r) : "v"(lo), "v"(hi)); return r;
}
__device__ inline float rcp_fast(float x) {
    float r; asm("v_rcp_f32 %0, %1" : "=v"(r) : "v"(x)); return r;
}
__device__ inline void plswap(unsigned& a, unsigned& b) {
    auto r = __builtin_amdgcn_permlane32_swap(a, b, false, false);
    a = r[0]; b = r[1];
}
__device__ inline float2 xhalves(float x) {
    unsigned u = __builtin_bit_cast(unsigned, x);
    auto r = __builtin_amdgcn_permlane32_swap(u, u, false, false);
    return make_float2(__builtin_bit_cast(float, r[0]),
                       __builtin_bit_cast(float, r[1]));
}
// Async global->LDS, 16B/lane. LDS dest = wave-uniform base + lane*16;
// swizzle lives in the per-lane GLOBAL source address (rule 21).
__device__ inline void gl_lds16(const void* gsrc, char* ldst) {
    __builtin_amdgcn_global_load_lds(
        (const __attribute__((address_space(1))) unsigned int*)gsrc,
        (__attribute__((address_space(3))) unsigned int*)ldst,
        16, 0, 0);
}

// ---------------------------------------------------------------------------
// Kernel 0: W f32 -> bf16 (one-time). 589824 elems, 8 per thread.
// ---------------------------------------------------------------------------
__global__ __launch_bounds__(256) void convw_kernel(
    const float* __restrict__ W, short* __restrict__ Wb)
{
    int i = (blockIdx.x * 256 + threadIdx.x) * 8;
    f32x4 a = *(const f32x4*)(W + i);
    f32x4 b = *(const f32x4*)(W + i + 4);
    uint4 pk;
    pk.x = cvt_pk_bf16(a[0], a[1]); pk.y = cvt_pk_bf16(a[2], a[3]);
    pk.z = cvt_pk_bf16(b[0], b[1]); pk.w = cvt_pk_bf16(b[2], b[3]);
    *(uint4*)(Wb + i) = pk;
}

// ---------------------------------------------------------------------------
// Kernel 1 (v10): Y = relu(X @ W^T) — W SHARED across q,k,v (t-loop in-step).
// v6 staged W per (input,m,n)-block: 442 MB of staged W traffic for a 1.18 MB
// matrix (75% of all staged bytes). v10: block = (m-pos, n-half), computes
// ALL THREE inputs; W staged once per K-step, consumed by 3 compute phases.
// Staged traffic 590 -> 295 MB; grid 256 = exactly 1 block/CU (single
// residency round vs v6's 1.5).
// - 512 thr / 8 waves; wave w owns cols [w*48,w*48+48); per-t acc[4][3]
//   (total acc 3x4x3 = 144 VGPR)
// - per K-step: stage {X_q,X_k,X_v 8KB each + W 24KB} = 48KB, dbuf (96KB LDS)
// - counted vmcnt(6) (T4): next step's 6 gl_lds issued, current step's drained
// - compute: 3 W-frag reads, then per t {8 f32-frag reads + cvt, 12 MFMA}
// ---------------------------------------------------------------------------
__global__ __launch_bounds__(512) void proj_kernel(
    const float* __restrict__ q, const float* __restrict__ k,
    const float* __restrict__ v, const short* __restrict__ Wb,
    short* __restrict__ q1, short* __restrict__ k1, short* __restrict__ v1t)
{
    __shared__ __align__(16) char lds[98304];
    // buf b at b*49152: X0@0 8K | X1@8192 | X2@16384 | W@24576 24K
    // epilogue overlay reuses [0,48K)

    int p  = blockIdx.x;
    int L  = (p & 7) * 32 + (p >> 3);        // 256 blocks = 8 XCD x 32
    int mt = L >> 1, nb = L & 1;             // 128 m-pos x 2 n-halves
    int m0 = mt << 6;                        // row offset within EACH input
    int n0 = nb * 384;

    int tid = threadIdx.x, lane = tid & 63, w = tid >> 6;   // w 0..7
    int l15 = lane & 15, g = lane >> 4;

    // X staging source (per-lane, pre-swizzled; same pattern all t)
    int xrow = w * 8 + (lane >> 3), xc = lane & 7;
    size_t xoff = (size_t)(m0 + xrow) * D_ + ((xc ^ (xrow & 7)) << 2);
    const float* xs0 = q + xoff;
    const float* xs1 = k + xoff;
    const float* xs2 = v + xoff;
    // W staging (as v6)
    int wrow0 = w * 48 + (lane >> 2), wc = lane & 3;
    int wrow1 = wrow0 + 16, wrow2 = wrow0 + 32;
    const short* wsrc0 = Wb + (size_t)(n0 + wrow0) * D_ + ((wc ^ ((wrow0 >> 1) & 3)) << 3);
    const short* wsrc1 = Wb + (size_t)(n0 + wrow1) * D_ + ((wc ^ ((wrow1 >> 1) & 3)) << 3);
    const short* wsrc2 = Wb + (size_t)(n0 + wrow2) * D_ + ((wc ^ ((wrow2 >> 1) & 3)) << 3);

#define ISSUE(s_, b_) do { int _ko = (s_) * 32; \
        char* _bb = lds + (b_) * 49152; \
        gl_lds16(xs0 + _ko, _bb + w * 1024); \
        gl_lds16(xs1 + _ko, _bb + 8192 + w * 1024); \
        gl_lds16(xs2 + _ko, _bb + 16384 + w * 1024); \
        gl_lds16(wsrc0 + _ko, _bb + 24576 + w * 3072); \
        gl_lds16(wsrc1 + _ko, _bb + 24576 + w * 3072 + 1024); \
        gl_lds16(wsrc2 + _ko, _bb + 24576 + w * 3072 + 2048); \
    } while (0)

    f32x4 acc[3][4][3];
    #pragma unroll
    for (int t = 0; t < 3; t++)
        #pragma unroll
        for (int m = 0; m < 4; m++)
            #pragma unroll
            for (int n = 0; n < 3; n++) acc[t][m][n] = (f32x4){0.f, 0.f, 0.f, 0.f};

    ISSUE(0, 0);
    for (int s = 0; s < 24; ++s) {
        __builtin_amdgcn_s_barrier();            // reads of target buf done
        asm volatile("" ::: "memory");
        if (s + 1 < 24) {
            ISSUE(s + 1, (s + 1) & 1);
            asm volatile("s_waitcnt vmcnt(6)" ::: "memory");   // step-s landed
        } else {
            asm volatile("s_waitcnt vmcnt(0)" ::: "memory");
        }
        __builtin_amdgcn_s_barrier();            // all waves' loads landed
        asm volatile("" ::: "memory");

        const char* bb = lds + (s & 1) * 49152;
        const char* Wp = bb + 24576;
        bf16x8 bfv[3];
        #pragma unroll
        for (int n = 0; n < 3; n++) {
            int r = w * 48 + n * 16 + l15;
            bfv[n] = *(const bf16x8*)(Wp + r * 64 + ((g ^ ((r >> 1) & 3)) << 4));
        }
        #pragma unroll
        for (int t = 0; t < 3; t++) {
            const char* Xb = bb + t * 8192;
            bf16x8 af[4];
            #pragma unroll
            for (int m = 0; m < 4; m++) {
                int r = m * 16 + l15;
                const char* rp = Xb + r * 128;
                f32x4 lo = *(const f32x4*)(rp + (((2 * g)     ^ (r & 7)) << 4));
                f32x4 hi = *(const f32x4*)(rp + (((2 * g + 1) ^ (r & 7)) << 4));
                uint4 pk;
                pk.x = cvt_pk_bf16(lo[0], lo[1]); pk.y = cvt_pk_bf16(lo[2], lo[3]);
                pk.z = cvt_pk_bf16(hi[0], hi[1]); pk.w = cvt_pk_bf16(hi[2], hi[3]);
                af[m] = __builtin_bit_cast(bf16x8, pk);
            }
            __builtin_amdgcn_s_setprio(1);
            #pragma unroll
            for (int m = 0; m < 4; m++)
                #pragma unroll
                for (int n = 0; n < 3; n++)
                    acc[t][m][n] = __builtin_amdgcn_mfma_f32_16x16x32_bf16(
                        af[m], bfv[n], acc[t][m][n], 0, 0, 0);
            __builtin_amdgcn_s_setprio(0);
        }
    }
#undef ISSUE

    // Epilogue (per t): relu(+scale) -> bf16 -> swizzled overlay -> b128 stores.
    // q/k overlay: [64 rows][48 chunks16B], slot = ch ^ (row&7)  (48KB)
    // v overlay  : [384 rows][8 chunks16B], slot = ch ^ (row&7)  (48KB)
    int bb2 = m0 >> 10;
    #pragma unroll
    for (int t = 0; t < 3; t++) {
        __syncthreads();
        const float sc1 = (t == 1) ? 0.18033688011112793f : 1.0f;  // 1/8*log2(e)
        #pragma unroll
        for (int m = 0; m < 4; m++)
            #pragma unroll
            for (int n = 0; n < 3; n++)
                #pragma unroll
                for (int r = 0; r < 4; r++) {
                    int row = m * 16 + g * 4 + r;
                    int col = w * 48 + n * 16 + l15;
                    short vv = f2bf(fmaxf(acc[t][m][n][r], 0.f) * sc1);
                    if (t == 2)   // v transposed: Ts[col 0..383][row 0..63]
                        *(short*)(lds + col * 128 + (((row >> 3) ^ (col & 7)) << 4)
                                  + ((row & 7) << 1)) = vv;
                    else          // Ts[row 0..63][col 0..383]
                        *(short*)(lds + row * 768 + (((col >> 3) ^ (row & 7)) << 4)
                                  + ((col & 7) << 1)) = vv;
                }
        __syncthreads();
        if (t == 2) {
            #pragma unroll
            for (int j = 0; j < 6; j++) {
                int c = tid * 6 + j;          // 3072 chunks: vr = c>>3, ch = c&7
                int vr = c >> 3, ch = c & 7;
                bf16x8 val = *(const bf16x8*)(lds + vr * 128 + ((ch ^ (vr & 7)) << 4));
                int gc = n0 + vr, h = gc >> 6, dh = gc & 63;
                *(bf16x8*)(v1t + (((size_t)bb2 * H_ + h) * DH_ + dh) * S_
                           + (m0 & 1023) + ch * 8) = val;
            }
        } else {
            short* dst0 = t ? k1 : q1;
            #pragma unroll
            for (int j = 0; j < 6; j++) {
                int c = tid * 6 + j;          // 3072 chunks: row = c/48, ch = c%48
                int row = c / 48, ch = c % 48;
                bf16x8 val = *(const bf16x8*)(lds + row * 768 + ((ch ^ (row & 7)) << 4));
                int m = m0 + row, ss = m & 1023;
                int gc = n0 + ch * 8, h = gc >> 6, dh = gc & 63;
                *(bf16x8*)(dst0 + (((size_t)bb2 * H_ + h) * S_ + ss) * DH_ + dh) = val;
            }
        }
    }
}

// ---------------------------------------------------------------------------
// Kernel 2 (v5): flash attention, swapped-QK^T 32x32x16, block-cooperative
// LDS-staged K/V (unchanged from round 6 -- passing, fast).
// ---------------------------------------------------------------------------
__global__ __launch_bounds__(256, 3) void attn_kernel(
    const short* __restrict__ q1, const short* __restrict__ k1,
    const short* __restrict__ v1t, float* __restrict__ out)
{
    __shared__ short Klds[2][4096];
    __shared__ short Vlds[2][4096];
    __shared__ float lsum_lds[4][32];

    int d    = blockIdx.x;
    int head = (d & 7) + ((d >> 6) << 3);
    int qi   = (d >> 3) & 7;
    int bb   = head / H_, hh = head % H_;

    int tid = threadIdx.x, lane = tid & 63, w = tid >> 6;
    int l31 = lane & 31, hi = lane >> 5;
    int qbase = (qi * 4 + w) * 32;

    const short* Qp = q1  + (size_t)head * S_ * DH_;
    const short* Kp = k1  + (size_t)head * S_ * DH_;
    const short* Vp = v1t + (size_t)head * DH_ * S_;

    int sr = tid >> 2, sc = tid & 3;
    int swz0 = sr * 128 + ((sc       ^ (sr & 7)) << 4);
    int swz1 = sr * 128 + (((sc + 4) ^ (sr & 7)) << 4);

    bf16x8 stK0, stK1, stV0, stV1;

#define LOADST(kvb) do { \
        const short* _kg = Kp + (size_t)((kvb) + sr) * DH_; \
        const short* _vg = Vp + (size_t)sr * S_ + (kvb); \
        stK0 = *(const bf16x8*)(_kg + sc * 8); \
        stK1 = *(const bf16x8*)(_kg + (sc + 4) * 8); \
        stV0 = *(const bf16x8*)(_vg + sc * 8); \
        stV1 = *(const bf16x8*)(_vg + (sc + 4) * 8); \
    } while (0)
#define WRITEST(buf) do { \
        char* _kb = (char*)&Klds[buf][0]; \
        char* _vb = (char*)&Vlds[buf][0]; \
        *(bf16x8*)(_kb + swz0) = stK0; \
        *(bf16x8*)(_kb + swz1) = stK1; \
        *(bf16x8*)(_vb + swz0) = stV0; \
        *(bf16x8*)(_vb + swz1) = stV1; \
    } while (0)

    bf16x8 qf[4];
    #pragma unroll
    for (int kb = 0; kb < 4; kb++)
        qf[kb] = *(const bf16x8*)(Qp + (size_t)(qbase + l31) * DH_ + kb * 16 + hi * 8);

    f32x16 o0, o1;
    #pragma unroll
    for (int r = 0; r < 16; r++) { o0[r] = 0.f; o1[r] = 0.f; }
    float mreg = -1e30f, lsum = 0.f;

    int xk = l31 & 7;

    auto subtile = [&](int cur, int j) {
        const char* Kt = (const char*)&Klds[cur][0];
        const char* Vt = (const char*)&Vlds[cur][0];
        int rK = (32 * j + l31) * 128;
        bf16x8 kf0 = *(const bf16x8*)(Kt + rK + (((0 + hi) ^ xk) << 4));
        bf16x8 kf1 = *(const bf16x8*)(Kt + rK + (((2 + hi) ^ xk) << 4));
        bf16x8 kf2 = *(const bf16x8*)(Kt + rK + (((4 + hi) ^ xk) << 4));
        bf16x8 kf3 = *(const bf16x8*)(Kt + rK + (((6 + hi) ^ xk) << 4));
        int rV0 = l31 * 128, rV1 = (32 + l31) * 128;
        int s0 = ((4 * j + hi) ^ xk) << 4, s1 = ((4 * j + 2 + hi) ^ xk) << 4;
        bf16x8 vf00 = *(const bf16x8*)(Vt + rV0 + s0);
        bf16x8 vf01 = *(const bf16x8*)(Vt + rV0 + s1);
        bf16x8 vf10 = *(const bf16x8*)(Vt + rV1 + s0);
        bf16x8 vf11 = *(const bf16x8*)(Vt + rV1 + s1);

        f32x16 s;
        #pragma unroll
        for (int r = 0; r < 16; r++) s[r] = 0.f;
        __builtin_amdgcn_s_setprio(1);
        s = __builtin_amdgcn_mfma_f32_32x32x16_bf16(kf0, qf[0], s, 0, 0, 0);
        s = __builtin_amdgcn_mfma_f32_32x32x16_bf16(kf1, qf[1], s, 0, 0, 0);
        s = __builtin_amdgcn_mfma_f32_32x32x16_bf16(kf2, qf[2], s, 0, 0, 0);
        s = __builtin_amdgcn_mfma_f32_32x32x16_bf16(kf3, qf[3], s, 0, 0, 0);
        __builtin_amdgcn_s_setprio(0);

        float t0 = fmaxf(s[0], s[1]),   t1 = fmaxf(s[2], s[3]);
        float t2 = fmaxf(s[4], s[5]),   t3 = fmaxf(s[6], s[7]);
        float t4 = fmaxf(s[8], s[9]),   t5 = fmaxf(s[10], s[11]);
        float t6 = fmaxf(s[12], s[13]), t7 = fmaxf(s[14], s[15]);
        float u0 = fmaxf(t0, t1), u1 = fmaxf(t2, t3);
        float u2 = fmaxf(t4, t5), u3 = fmaxf(t6, t7);
        float pmax = fmaxf(fmaxf(u0, u1), fmaxf(u2, u3));
        float2 ph = xhalves(pmax);
        pmax = fmaxf(ph.x, ph.y);

        if (!__all(pmax <= mreg + 8.f)) {
            float mn = fmaxf(mreg, pmax);
            float sc_ = exp2_fast(mreg - mn);
            mreg = mn; lsum *= sc_;
            if (hi == 0) lsum_lds[w][l31] = sc_;
            asm volatile("s_waitcnt lgkmcnt(0)" ::: "memory");
            #pragma unroll
            for (int r = 0; r < 16; r++) {
                int crow = (r & 3) + ((r >> 2) << 3) + (hi << 2);
                float srw = lsum_lds[w][crow];
                o0[r] *= srw; o1[r] *= srw;
            }
        }

        #pragma unroll
        for (int r = 0; r < 16; r++) s[r] = exp2_fast(s[r] - mreg);

        float a0 = s[0] + s[1],   a1 = s[2] + s[3];
        float a2 = s[4] + s[5],   a3 = s[6] + s[7];
        float a4 = s[8] + s[9],   a5 = s[10] + s[11];
        float a6 = s[12] + s[13], a7 = s[14] + s[15];
        float rsum = ((a0 + a1) + (a2 + a3)) + ((a4 + a5) + (a6 + a7));
        float2 rh = xhalves(rsum);
        lsum += rh.x + rh.y;

        unsigned c0 = cvt_pk_bf16(s[0], s[1]);
        unsigned c1 = cvt_pk_bf16(s[2], s[3]);
        unsigned c2 = cvt_pk_bf16(s[4], s[5]);
        unsigned c3 = cvt_pk_bf16(s[6], s[7]);
        unsigned c4 = cvt_pk_bf16(s[8], s[9]);
        unsigned c5 = cvt_pk_bf16(s[10], s[11]);
        unsigned c6 = cvt_pk_bf16(s[12], s[13]);
        unsigned c7 = cvt_pk_bf16(s[14], s[15]);
        plswap(c0, c2);
        plswap(c1, c3);
        plswap(c4, c6);
        plswap(c5, c7);

        union U { unsigned u[4]; bf16x8 v; };
        U f0, f1;
        f0.u[0] = c0; f0.u[1] = c1; f0.u[2] = c2; f0.u[3] = c3;
        f1.u[0] = c4; f1.u[1] = c5; f1.u[2] = c6; f1.u[3] = c7;

        __builtin_amdgcn_s_setprio(1);
        o0 = __builtin_amdgcn_mfma_f32_32x32x16_bf16(f0.v, vf00, o0, 0, 0, 0);
        o0 = __builtin_amdgcn_mfma_f32_32x32x16_bf16(f1.v, vf01, o0, 0, 0, 0);
        o1 = __builtin_amdgcn_mfma_f32_32x32x16_bf16(f0.v, vf10, o1, 0, 0, 0);
        o1 = __builtin_amdgcn_mfma_f32_32x32x16_bf16(f1.v, vf11, o1, 0, 0, 0);
        __builtin_amdgcn_s_setprio(0);
    };

    LOADST(0);
    WRITEST(0);
    LOADST(64);
    asm volatile("s_waitcnt lgkmcnt(0)" ::: "memory");
    __builtin_amdgcn_s_barrier();
    asm volatile("" ::: "memory");

    int cur = 0;
    for (int t = 0; t < 16; t++) {
        if (t < 15) {
            WRITEST(cur ^ 1);
            if (t < 14) LOADST((t + 2) * 64);
        }
        subtile(cur, 0);
        subtile(cur, 1);
        if (t < 15) {
            asm volatile("" ::: "memory");
            asm volatile("s_waitcnt lgkmcnt(0)" ::: "memory");
            __builtin_amdgcn_s_barrier();
            asm volatile("" ::: "memory");
        }
        cur ^= 1;
    }
#undef LOADST
#undef WRITEST

    if (hi == 0) lsum_lds[w][l31] = lsum;
    asm volatile("s_waitcnt lgkmcnt(0)" ::: "memory");
    #pragma unroll
    for (int r = 0; r < 16; r++) {
        int crow = (r & 3) + ((r >> 2) << 3) + (hi << 2);
        float inv = rcp_fast(lsum_lds[w][crow]);
        float* op = out + ((size_t)(bb * S_ + qbase + crow)) * D_ + hh * DH_ + l31;
        op[0]  = o0[r] * inv;
        op[32] = o1[r] * inv;
    }
}

// ---------------------------------------------------------------------------
// Kernel 3 (v2): y = LN(2*out + q) * gamma + beta; 192 thr/row, f32x4 loads.
// ---------------------------------------------------------------------------
__global__ __launch_bounds__(192) void ln_kernel(
    const float* __restrict__ qin, const float* __restrict__ gamma,
    const float* __restrict__ beta, float* __restrict__ out)
{
    int row = blockIdx.x;
    int tid = threadIdx.x;
    size_t base = (size_t)row * D_ + tid * 4;

    f32x4 o  = *(const f32x4*)(out + base);
    f32x4 qv = *(const f32x4*)(qin + base);
    f32x4 x;
    float sum = 0.f, sq = 0.f;
    #pragma unroll
    for (int i = 0; i < 4; i++) {
        x[i] = 2.f * o[i] + qv[i];
        sum += x[i];
        sq  += x[i] * x[i];
    }
    #pragma unroll
    for (int msk = 1; msk < 64; msk <<= 1) {
        sum += __shfl_xor(sum, msk);
        sq  += __shfl_xor(sq, msk);
    }
    __shared__ float s1[3], s2[3];
    if ((tid & 63) == 0) { s1[tid >> 6] = sum; s2[tid >> 6] = sq; }
    __syncthreads();
    sum = s1[0] + s1[1] + s1[2];
    sq  = s2[0] + s2[1] + s2[2];
    float mu   = sum * (1.f / D_);
    float var  = sq * (1.f / D_) - mu * mu;
    float rstd = rsqrtf(var + 1e-5f);
    f32x4 g = *(const f32x4*)(gamma + tid * 4);
    f32x4 b = *(const f32x4*)(beta + tid * 4);
    f32x4 y;
    #pragma unroll
    for (int i = 0; i < 4; i++)
        y[i] = (x[i] - mu) * rstd * g[i] + b[i];
    *(f32x4*)(out + base) = y;
}

// ---------------------------------------------------------------------------
extern "C" void kernel_launch(void* const* d_in, const int* in_sizes, int n_in,
                              void* d_out, int out_size, void* d_ws, size_t ws_size,
                              hipStream_t stream)
{
    const float* q     = (const float*)d_in[0];
    const float* k     = (const float*)d_in[1];
    const float* v     = (const float*)d_in[2];
    const float* W     = (const float*)d_in[3];
    const float* gamma = (const float*)d_in[4];
    const float* beta  = (const float*)d_in[5];

    size_t per = (size_t)B_ * H_ * S_ * DH_;   // 6291456
    short* q1  = (short*)d_ws;
    short* k1  = q1 + per;
    short* v1t = k1 + per;
    short* Wb  = v1t + per;                    // +1.18 MB (total ~38.9 MB)
    float* out = (float*)d_out;

    convw_kernel<<<dim3(288), dim3(256), 0, stream>>>(W, Wb);
    // 128 m-positions x 2 n-halves = 256 blocks, 512 threads, all 3 inputs each
    proj_kernel<<<dim3(256), dim3(512), 0, stream>>>(q, k, v, Wb, q1, k1, v1t);
    attn_kernel<<<dim3(768), dim3(256), 0, stream>>>(q1, k1, v1t, out);
    ln_kernel<<<dim3(B_ * S_), dim3(192), 0, stream>>>(q, gamma, beta, out);
}